// Round 8
// baseline (1435.852 us; speedup 1.0000x reference)
//
#include <hip/hip_runtime.h>
#include <math.h>

// Problem constants (fixed shapes from setup_inputs)
#define Dn   12
#define Hn   448
#define Wn   224
#define HWn  (Hn*Wn)        // 100352
#define DHWn (Dn*HWn)       // 1204224
#define Cn   10

// Twiddle table (float2 in global):
#define TW_W32   0     // 16: W32^j
#define TW_W7    30    // 7:  W7^j
#define TW_B224  69    // 32: W224^j (j<32)
#define TW_B448L 101   // 64: W448^a (a<64)  -- colfft lane twiddle
#define TW_W64   165   // 32: W64^j (j<32)
#define TW_N2    197

// ---------- complex helpers ----------
__device__ __forceinline__ float2 cmul(float2 a, float2 b) {
    return make_float2(fmaf(a.x, b.x, -a.y * b.y), fmaf(a.x, b.y, a.y * b.x));
}
__device__ __forceinline__ float2 cfma(float2 a, float2 b, float2 acc) {
    acc.x = fmaf(a.x, b.x, fmaf(-a.y, b.y, acc.x));
    acc.y = fmaf(a.x, b.y, fmaf(a.y, b.x, acc.y));
    return acc;
}
__device__ __forceinline__ float2 cadd(float2 a, float2 b) { return make_float2(a.x + b.x, a.y + b.y); }
__device__ __forceinline__ float2 csub(float2 a, float2 b) { return make_float2(a.x - b.x, a.y - b.y); }
__host__ __device__ constexpr int brev5(int i) {
    return ((i & 1) << 4) | ((i & 2) << 2) | (i & 4) | ((i & 8) >> 2) | ((i & 16) >> 4);
}

__device__ __forceinline__ float2 shflx2(float2 v, int m) {
    return make_float2(__shfl_xor(v.x, m, 64), __shfl_xor(v.y, m, 64));
}

__device__ __forceinline__ double waveReduce(double v) {
#pragma unroll
    for (int o = 32; o > 0; o >>= 1) v += __shfl_down(v, o, 64);
    return v;
}

// log-depth twiddle powers tp[j] = base^j (depth <= 4)
template<int NP>
__device__ __forceinline__ void twpow(float2 (&tp)[NP], float2 base) {
    tp[0] = make_float2(1.f, 0.f);
    tp[1] = base;
#pragma unroll
    for (int j = 2; j < NP; ++j) tp[j] = cmul(tp[j >> 1], tp[j - (j >> 1)]);
}

// ---------- init kernels ----------
__global__ void k_init_misc(float2* __restrict__ tws, double* __restrict__ S) {
    int t = threadIdx.x;  // 256 threads
    const double PI2 = 6.283185307179586476925287;
    if (t < 16)             { double s, c; sincos(-(PI2 * t) / 32.0,  &s, &c); tws[TW_W32 + t]  = make_float2((float)c, (float)s); }
    if (t >= 30 && t < 37)  { int j = t - 30; double s, c; sincos(-(PI2 * j) / 7.0,  &s, &c); tws[TW_W7 + j]  = make_float2((float)c, (float)s); }
    if (t >= 69 && t < 101) { int j = t - 69; double s, c; sincos(-(PI2 * j) / 224.0, &s, &c); tws[TW_B224 + j] = make_float2((float)c, (float)s); }
    if (t >= 101 && t < 165){ int j = t - 101; double s, c; sincos(-(PI2 * j) / 448.0, &s, &c); tws[TW_B448L + j] = make_float2((float)c, (float)s); }
    if (t >= 165 && t < 197){ int j = t - 165; double s, c; sincos(-(PI2 * j) / 64.0,  &s, &c); tws[TW_W64 + j]  = make_float2((float)c, (float)s); }
    if (t >= 197 && t < 229) S[t - 197] = 0.0;
}

__global__ void k_build_p(const float* __restrict__ z, const float* __restrict__ zf,
                          const float* __restrict__ miu,
                          float2* __restrict__ p, float2* __restrict__ r, float2* __restrict__ b,
                          double* __restrict__ S) {
    float mu = fabsf(miu[0]);
    double acc = 0.0;
    for (int e = blockIdx.x * blockDim.x + threadIdx.x; e < DHWn; e += gridDim.x * blockDim.x) {
        int d = e / HWn, rem = e - d * HWn;
        int h = rem / Wn, w = rem - h * Wn;
        int hs = h + Hn / 2; if (hs >= Hn) hs -= Hn;
        int ws = w + Wn / 2; if (ws >= Wn) ws -= Wn;
        int src = d * HWn + hs * Wn + ws;
        float pr = fmaf(mu, z[src], zf[src]);
        float pi = fmaf(mu, z[DHWn + src], zf[DHWn + src]);
        float2 v = make_float2(pr, pi);
        p[e] = v; r[e] = v; b[e] = make_float2(0.f, 0.f);
        acc += (double)pr * pr + (double)pi * pi;
    }
    acc = waveReduce(acc);
    if ((threadIdx.x & 63) == 0) atomicAdd(&S[0], acc);
}

__global__ void k_build_coil(const float* __restrict__ cr, const float* __restrict__ ci,
                             float2* __restrict__ coil) {
    for (int e = blockIdx.x * blockDim.x + threadIdx.x; e < Cn * HWn; e += gridDim.x * blockDim.x) {
        int c = e / HWn, rem = e - c * HWn;
        int h = rem / Wn, w = rem - h * Wn;
        int hs = h + Hn / 2; if (hs >= Hn) hs -= Hn;
        int ws = w + Wn / 2; if (ws >= Wn) ws -= Wn;
        int src = c * HWn + hs * Wn + ws;
        coil[e] = make_float2(cr[src], ci[src]);
    }
}

// permuted + shifted + scaled mask: maskP[L*448 + h], line L holds true
// frequency column w(L) = 7*brev5(L&31) + (L>>5)
__global__ void k_build_mask(const int* __restrict__ mask, float* __restrict__ maskP) {
    for (int e = blockIdx.x * blockDim.x + threadIdx.x; e < HWn; e += gridDim.x * blockDim.x) {
        int L = e / Hn, h = e - L * Hn;
        int w = 7 * brev5(L & 31) + (L >> 5);
        int hs = h + Hn / 2; if (hs >= Hn) hs -= Hn;
        int ws = w + Wn / 2; if (ws >= Wn) ws -= Wn;
        maskP[e] = (float)mask[hs * Wn + ws] * (1.0f / (float)HWn);
    }
}

// ---------- forward row FFT (224 = 7*32 lane-FFT), coil-mul, write Y1T lines ----------
#define BPITCH 226
__global__ __launch_bounds__(256) void k_rowfft0(const float2* __restrict__ P,
                                                 const float2* __restrict__ coil,
                                                 float2* __restrict__ Y1T,
                                                 const float2* __restrict__ twg,
                                                 int chunkStart) {
    __shared__ float2 buf[8][BPITCH];
    int tid = threadIdx.x;
    int lane = tid & 63, wv = tid >> 6, hi = lane >> 5, l32 = lane & 31;
    int h0 = blockIdx.x * 8, d = blockIdx.y, cz = blockIdx.z;
    int row = h0 + 2 * wv + hi;
    const float2* w32g = twg + TW_W32;
    const float2* w7g  = twg + TW_W7;
    const float2* b224 = twg + TW_B224;

    const float2* prow = P + (size_t)d * HWn + (size_t)row * Wn;
    const float2* crow = coil + (size_t)(chunkStart + cz) * HWn + (size_t)row * Wn;

    float2 xb[7];
#pragma unroll
    for (int b = 0; b < 7; ++b) xb[b] = cmul(prow[32 * b + l32], crow[32 * b + l32]);

    // DFT7
    float2 y[7];
#pragma unroll
    for (int d7 = 0; d7 < 7; ++d7) {
        float2 s = xb[0];
#pragma unroll
        for (int b = 1; b < 7; ++b) s = cfma(xb[b], w7g[(b * d7) % 7], s);
        y[d7] = s;
    }
    // twiddle W224^{l32*d7}
    float2 tp[7]; twpow(tp, b224[l32]);
#pragma unroll
    for (int d7 = 1; d7 < 7; ++d7) y[d7] = cmul(y[d7], tp[d7]);

    // FFT32 across each half-wave, DIF (select form — measured best)
#pragma unroll
    for (int s = 0; s < 5; ++s) {
        int dist = 16 >> s;
        float2 wst = w32g[(l32 & (dist - 1)) << s];
        bool h2 = (l32 & dist) != 0;
#pragma unroll
        for (int d7 = 0; d7 < 7; ++d7) {
            float2 t = shflx2(y[d7], dist);
            float2 sum = cadd(y[d7], t);
            float2 dif = cmul(csub(t, y[d7]), wst);
            y[d7] = h2 ? dif : sum;
        }
    }

    // deposit to LDS: line L = d7*32 + l32
#pragma unroll
    for (int d7 = 0; d7 < 7; ++d7) buf[2 * wv + hi][d7 * 32 + l32] = y[d7];
    __syncthreads();

    float2* img = Y1T + ((size_t)cz * Dn + d) * (size_t)HWn;
#pragma unroll
    for (int k = 0; k < 7; ++k) {
        int i = tid + k * 256;
        int hh = i & 7, L = i >> 3;
        img[(size_t)L * Hn + h0 + hh] = buf[hh][L];
    }
}

// ---------- column FFT448 + mask + IFFT448, pure register lane-FFT ----------
__global__ __launch_bounds__(256) void k_colfft(float2* __restrict__ Y1T,
                                                const float* __restrict__ maskP,
                                                const float2* __restrict__ twg) {
    __shared__ float2 tws[TW_N2];
    int tid = threadIdx.x;
    int lane = tid & 63, wv = tid >> 6;
    for (int i = tid; i < TW_N2; i += 256) tws[i] = twg[i];
    __syncthreads();

    const float2* w7t  = tws + TW_W7;
    const float2* w64t = tws + TW_W64;
    const float2* b448l = tws + TW_B448L;

    int L = blockIdx.x * 4 + wv;
    int d = blockIdx.y, cz = blockIdx.z;
    float2* line = Y1T + ((size_t)cz * Dn + d) * (size_t)HWn + (size_t)L * Hn;

    float2 xb[7];
#pragma unroll
    for (int b = 0; b < 7; ++b) xb[b] = line[64 * b + lane];

    // forward DFT7
    float2 y[7];
#pragma unroll
    for (int d7 = 0; d7 < 7; ++d7) {
        float2 s = xb[0];
#pragma unroll
        for (int b = 1; b < 7; ++b) s = cfma(xb[b], w7t[(b * d7) % 7], s);
        y[d7] = s;
    }
    float2 tp[7]; twpow(tp, b448l[lane]);
#pragma unroll
    for (int d7 = 1; d7 < 7; ++d7) y[d7] = cmul(y[d7], tp[d7]);

    // FFT64 across lanes, DIF (select form)
#pragma unroll
    for (int s = 0; s < 6; ++s) {
        int dist = 32 >> s;
        float2 wst = w64t[(lane & (dist - 1)) << s];
        bool hi = (lane & dist) != 0;
#pragma unroll
        for (int d7 = 0; d7 < 7; ++d7) {
            float2 t = shflx2(y[d7], dist);
            float2 sum = cadd(y[d7], t);
            float2 dif = cmul(csub(t, y[d7]), wst);
            y[d7] = hi ? dif : sum;
        }
    }

    // mask: lane holds H-freq index 7*brev6(lane)+d7
    int rb = (brev5(lane & 31) << 1) | (lane >> 5);
    const float* mrow = maskP + (size_t)L * Hn + 7 * rb;
#pragma unroll
    for (int d7 = 0; d7 < 7; ++d7) {
        float m = mrow[d7];
        y[d7].x *= m; y[d7].y *= m;
    }

    // inverse FFT64, DIT (select form)
#pragma unroll
    for (int s = 0; s < 6; ++s) {
        int dist = 1 << s;
        float2 wst = w64t[(lane & (dist - 1)) << (5 - s)];
        wst.y = -wst.y;
        bool hi = (lane & dist) != 0;
#pragma unroll
        for (int d7 = 0; d7 < 7; ++d7) {
            float2 t = shflx2(y[d7], dist);
            float2 uu = hi ? t : y[d7];
            float2 vv = hi ? y[d7] : t;
            float2 wtv = cmul(vv, wst);
            y[d7] = hi ? csub(uu, wtv) : cadd(uu, wtv);
        }
    }
#pragma unroll
    for (int d7 = 1; d7 < 7; ++d7) {
        float2 c = make_float2(tp[d7].x, -tp[d7].y);
        y[d7] = cmul(y[d7], c);
    }
#pragma unroll
    for (int b = 0; b < 7; ++b) {
        float2 s = y[0];
#pragma unroll
        for (int d7 = 1; d7 < 7; ++d7) {
            float2 wq = w7t[(b * d7) % 7]; wq.y = -wq.y;
            s = cfma(y[d7], wq, s);
        }
        xb[b] = s;
    }
#pragma unroll
    for (int b = 0; b < 7; ++b) line[64 * b + lane] = xb[b];
}

// ---------- fused inverse row FFT + conj-coil + partial coil-sum ----------
// z-split: block z handles coils [base, base+cnt) of the chunk, writes Qpart[z].
// Register-prefetch pipeline on the Y1T strips + coil rows.
__global__ __launch_bounds__(256) void k_irow_combine(const float2* __restrict__ Y1T,
                                                      const float2* __restrict__ coil,
                                                      float2* __restrict__ Qpart,
                                                      const float2* __restrict__ twg,
                                                      int cc, int chunkStart, int first) {
    __shared__ float2 buf[8][BPITCH];
    int tid = threadIdx.x;
    int lane = tid & 63, wv = tid >> 6, hi = lane >> 5, l32 = lane & 31;
    int h0 = blockIdx.x * 8, d = blockIdx.y, zp = blockIdx.z;
    int row = h0 + 2 * wv + hi;
    const float2* w32g = twg + TW_W32;
    const float2* w7g  = twg + TW_W7;
    const float2* b224 = twg + TW_B224;

    int half = (cc + 1) >> 1;
    int base = zp * half;
    int cnt = cc - base; if (cnt > half) cnt = half; if (cnt < 0) cnt = 0;

    float2 tp[7]; twpow(tp, b224[l32]);

    float2 acc[7];
#pragma unroll
    for (int b = 0; b < 7; ++b) acc[b] = make_float2(0.f, 0.f);

    // prefetch strip for first coil of our range
    float2 pre[7];
    if (cnt > 0) {
        const float2* img0 = Y1T + ((size_t)base * Dn + d) * (size_t)HWn;
#pragma unroll
        for (int k = 0; k < 7; ++k) {
            int i = tid + k * 256;
            int hh = i & 7, L = i >> 3;
            pre[k] = img0[(size_t)L * Hn + h0 + hh];
        }
    }

    for (int j = 0; j < cnt; ++j) {
        int cz = base + j;
        __syncthreads();   // previous compute finished reading buf
#pragma unroll
        for (int k = 0; k < 7; ++k) {
            int i = tid + k * 256;
            int hh = i & 7, L = i >> 3;
            buf[hh][L] = pre[k];
        }
        __syncthreads();

        // prefetch next strip (overlaps compute below)
        if (j + 1 < cnt) {
            const float2* imgn = Y1T + ((size_t)(cz + 1) * Dn + d) * (size_t)HWn;
#pragma unroll
            for (int k = 0; k < 7; ++k) {
                int i = tid + k * 256;
                int hh = i & 7, L = i >> 3;
                pre[k] = imgn[(size_t)L * Hn + h0 + hh];
            }
        }
        // prefetch this coil's row
        const float2* crow = coil + (size_t)(chunkStart + cz) * HWn + (size_t)row * Wn;
        float2 cpre[7];
#pragma unroll
        for (int b = 0; b < 7; ++b) cpre[b] = crow[32 * b + l32];

        // lane l32 reads line L = d7*32 + l32 (DIT-ready bit-rev order)
        float2 y[7];
#pragma unroll
        for (int d7 = 0; d7 < 7; ++d7) y[d7] = buf[2 * wv + hi][d7 * 32 + l32];

        // inverse FFT32 across half-wave, DIT (select form)
#pragma unroll
        for (int s = 0; s < 5; ++s) {
            int dist = 1 << s;
            float2 wst = w32g[(l32 & (dist - 1)) << (4 - s)];
            wst.y = -wst.y;
            bool h2 = (l32 & dist) != 0;
#pragma unroll
            for (int d7 = 0; d7 < 7; ++d7) {
                float2 t = shflx2(y[d7], dist);
                float2 uu = h2 ? t : y[d7];
                float2 vv = h2 ? y[d7] : t;
                float2 wtv = cmul(vv, wst);
                y[d7] = h2 ? csub(uu, wtv) : cadd(uu, wtv);
            }
        }
        // conj twiddle W224^{-l32*d7}
#pragma unroll
        for (int d7 = 1; d7 < 7; ++d7) {
            float2 c = make_float2(tp[d7].x, -tp[d7].y);
            y[d7] = cmul(y[d7], c);
        }
        // inverse DFT7 + conj-coil accumulate
#pragma unroll
        for (int b = 0; b < 7; ++b) {
            float2 s = y[0];
#pragma unroll
            for (int d7 = 1; d7 < 7; ++d7) {
                float2 wq = w7g[(b * d7) % 7]; wq.y = -wq.y;
                s = cfma(y[d7], wq, s);
            }
            float2 c = cpre[b];
            acc[b].x += fmaf(s.x, c.x, s.y * c.y);
            acc[b].y += fmaf(s.y, c.x, -s.x * c.y);
        }
    }

    // write partial sum (plain stores; k_dot merges halves)
    float2* qrow = Qpart + (size_t)zp * DHWn + (size_t)d * HWn + (size_t)row * Wn;
#pragma unroll
    for (int b = 0; b < 7; ++b) {
        float2 s0 = acc[b];
        if (!first) s0 = cadd(qrow[32 * b + l32], s0);
        qrow[32 * b + l32] = s0;
    }
}

// ---------- merge partials + mu*p, write Q, compute qp dot ----------
__global__ void k_dot(const float4* __restrict__ P, const float4* __restrict__ Q0,
                      const float4* __restrict__ Q1, float4* __restrict__ Q,
                      const float* __restrict__ miu, double* __restrict__ S, int it) {
    float mu = fabsf(miu[0]);
    double ar = 0.0, ai = 0.0;
    const int N2 = DHWn / 2;
    for (int e = blockIdx.x * blockDim.x + threadIdx.x; e < N2; e += gridDim.x * blockDim.x) {
        float4 pv = P[e], a = Q0[e], b = Q1[e];
        float4 q;
        q.x = fmaf(mu, pv.x, a.x + b.x);
        q.y = fmaf(mu, pv.y, a.y + b.y);
        q.z = fmaf(mu, pv.z, a.z + b.z);
        q.w = fmaf(mu, pv.w, a.w + b.w);
        Q[e] = q;
        ar += (double)(q.x * pv.x + q.y * pv.y) + (double)(q.z * pv.z + q.w * pv.w);
        ai += (double)(q.y * pv.x - q.x * pv.y) + (double)(q.w * pv.z - q.z * pv.w);
    }
    ar = waveReduce(ar);
    ai = waveReduce(ai);
    if ((threadIdx.x & 63) == 0) {
        atomicAdd(&S[8 + it], ar);
        atomicAdd(&S[16 + it], ai);
    }
}

// ---------- CG scalar updates (float4 = 2 complex per lane) ----------
__global__ void k_update_br(const double* __restrict__ Sin, double* __restrict__ S, int it,
                            const float4* __restrict__ p, const float4* __restrict__ q,
                            float4* __restrict__ b, float4* __restrict__ r) {
    double rr = Sin[it], qr = Sin[8 + it], qi = Sin[16 + it];
    double den = qr * qr + qi * qi;
    float arf = (float)(rr * qr / den);
    float aif = (float)(-rr * qi / den);
    double acc = 0.0;
    const int N2 = DHWn / 2;
    for (int e = blockIdx.x * blockDim.x + threadIdx.x; e < N2; e += gridDim.x * blockDim.x) {
        float4 pv = p[e], qv = q[e], bv = b[e], rv = r[e];
        bv.x += arf * pv.x - aif * pv.y;  bv.y += arf * pv.y + aif * pv.x;
        bv.z += arf * pv.z - aif * pv.w;  bv.w += arf * pv.w + aif * pv.z;
        b[e] = bv;
        rv.x -= arf * qv.x - aif * qv.y;  rv.y -= arf * qv.y + aif * qv.x;
        rv.z -= arf * qv.z - aif * qv.w;  rv.w -= arf * qv.w + aif * qv.z;
        r[e] = rv;
        acc += (double)rv.x * rv.x + (double)rv.y * rv.y
             + (double)rv.z * rv.z + (double)rv.w * rv.w;
    }
    acc = waveReduce(acc);
    if ((threadIdx.x & 63) == 0) atomicAdd(&S[it + 1], acc);
}

__global__ void k_update_p(const double* __restrict__ S, int it,
                           const float4* __restrict__ r, float4* __restrict__ p) {
    float beta = (float)(S[it + 1] / S[it]);
    const int N2 = DHWn / 2;
    for (int e = blockIdx.x * blockDim.x + threadIdx.x; e < N2; e += gridDim.x * blockDim.x) {
        float4 rv = r[e], pv = p[e];
        p[e] = make_float4(fmaf(beta, pv.x, rv.x), fmaf(beta, pv.y, rv.y),
                           fmaf(beta, pv.z, rv.z), fmaf(beta, pv.w, rv.w));
    }
}

__global__ void k_output(const float2* __restrict__ b, float* __restrict__ out) {
    for (int e = blockIdx.x * blockDim.x + threadIdx.x; e < DHWn; e += gridDim.x * blockDim.x) {
        int d = e / HWn, rem = e - d * HWn;
        int h = rem / Wn, w = rem - h * Wn;
        int hs = h + Hn / 2; if (hs >= Hn) hs -= Hn;
        int ws = w + Wn / 2; if (ws >= Wn) ws -= Wn;
        float2 v = b[d * HWn + hs * Wn + ws];
        out[e] = v.x;
        out[DHWn + e] = v.y;
    }
}

extern "C" void kernel_launch(void* const* d_in, const int* in_sizes, int n_in,
                              void* d_out, int out_size, void* d_ws, size_t ws_size,
                              hipStream_t stream) {
    const float* z      = (const float*)d_in[0];
    const float* zf     = (const float*)d_in[1];
    const float* coil_r = (const float*)d_in[2];
    const float* coil_i = (const float*)d_in[3];
    const int*   maskp  = (const int*)d_in[4];
    const float* miu    = (const float*)d_in[5];
    float* out = (float*)d_out;

    char* w = (char*)d_ws;
    size_t off = 0;
    auto carve = [&](size_t bytes) -> void* {
        void* ptr = w + off;
        off += (bytes + 511) & ~(size_t)511;
        return ptr;
    };
    float2* P     = (float2*)carve((size_t)DHWn * 8);
    float2* R     = (float2*)carve((size_t)DHWn * 8);
    float2* Bv    = (float2*)carve((size_t)DHWn * 8);
    float2* Q     = (float2*)carve((size_t)DHWn * 8);
    float2* QP    = (float2*)carve((size_t)2 * DHWn * 8);   // two partial-sum buffers
    float2* COIL  = (float2*)carve((size_t)Cn * HWn * 8);
    float*  MASKP = (float*)carve((size_t)HWn * 4);
    float2* TWS   = (float2*)carve(TW_N2 * 8);
    double* S     = (double*)carve(64 * 8);

    size_t imgSet = (size_t)DHWn * 8;   // one coil-slot (12 slices), 9.63 MB
    int cc = 1;
    {
        const int opts[4] = {10, 5, 2, 1};
        for (int i = 0; i < 4; ++i) {
            if (off + (size_t)opts[i] * imgSet <= ws_size) { cc = opts[i]; break; }
        }
    }
    float2* Y1T = (float2*)carve((size_t)cc * imgSet);   // staged lines [c][d][L][h]
    int nch = Cn / cc;

    k_init_misc<<<1, 256, 0, stream>>>(TWS, S);
    k_build_p<<<1024, 256, 0, stream>>>(z, zf, miu, P, R, Bv, S);
    k_build_coil<<<1024, 256, 0, stream>>>(coil_r, coil_i, COIL);
    k_build_mask<<<512, 256, 0, stream>>>(maskp, MASKP);

    for (int it = 0; it < 5; ++it) {
        for (int ch = 0; ch < nch; ++ch) {
            int cs = ch * cc;
            dim3 gf(Hn / 8, Dn, cc);   // 56 x 12 x cc
            dim3 gc(Wn / 4, Dn, cc);   // 56 x 12 x cc
            dim3 gi(Hn / 8, Dn, 2);    // 56 x 12 x 2 (coil halves)
            k_rowfft0<<<gf, 256, 0, stream>>>(P, COIL, Y1T, TWS, cs);
            k_colfft<<<gc, 256, 0, stream>>>(Y1T, MASKP, TWS);
            k_irow_combine<<<gi, 256, 0, stream>>>(Y1T, COIL, QP, TWS, cc, cs,
                                                   ch == 0 ? 1 : 0);
        }
        k_dot<<<1024, 256, 0, stream>>>((const float4*)P, (const float4*)QP,
                                        (const float4*)(QP + DHWn), (float4*)Q,
                                        miu, S, it);
        k_update_br<<<1024, 256, 0, stream>>>(S, S, it, (const float4*)P, (const float4*)Q,
                                              (float4*)Bv, (float4*)R);
        if (it < 4) k_update_p<<<1024, 256, 0, stream>>>(S, it, (const float4*)R, (float4*)P);
    }
    k_output<<<1024, 256, 0, stream>>>(Bv, out);
}

// Round 9
// 1269.843 us; speedup vs baseline: 1.1307x; 1.1307x over previous
//
#include <hip/hip_runtime.h>
#include <math.h>

// Problem constants (fixed shapes from setup_inputs)
#define Dn   12
#define Hn   448
#define Wn   224
#define HWn  (Hn*Wn)        // 100352
#define DHWn (Dn*HWn)       // 1204224
#define Cn   10

// Twiddle table (float2 in global):
#define TW_W32   0     // 16:  W32^j
#define TW_W7    16    // 7:   W7^j
#define TW_W64   23    // 32:  W64^j
#define TW_T224  55    // 224: W224^{d7*l32}  [d7*32+l32]
#define TW_T448  279   // 448: W448^{d7*lane} [d7*64+lane]
#define TW_NT    727

// ---------- complex helpers ----------
__device__ __forceinline__ float2 cmul(float2 a, float2 b) {
    return make_float2(fmaf(a.x, b.x, -a.y * b.y), fmaf(a.x, b.y, a.y * b.x));
}
__device__ __forceinline__ float2 cfma(float2 a, float2 b, float2 acc) {
    acc.x = fmaf(a.x, b.x, fmaf(-a.y, b.y, acc.x));
    acc.y = fmaf(a.x, b.y, fmaf(a.y, b.x, acc.y));
    return acc;
}
__device__ __forceinline__ float2 cadd(float2 a, float2 b) { return make_float2(a.x + b.x, a.y + b.y); }
__device__ __forceinline__ float2 csub(float2 a, float2 b) { return make_float2(a.x - b.x, a.y - b.y); }
__host__ __device__ constexpr int brev5(int i) {
    return ((i & 1) << 4) | ((i & 2) << 2) | (i & 4) | ((i & 8) >> 2) | ((i & 16) >> 4);
}

__device__ __forceinline__ float2 shflx2(float2 v, int m) {
    return make_float2(__shfl_xor(v.x, m, 64), __shfl_xor(v.y, m, 64));
}

__device__ __forceinline__ double waveReduce(double v) {
#pragma unroll
    for (int o = 32; o > 0; o >>= 1) v += __shfl_down(v, o, 64);
    return v;
}

// ---------- init kernels ----------
__global__ void k_init_misc(float2* __restrict__ tws, double* __restrict__ S) {
    int t = threadIdx.x;  // 1024 threads
    const double PI2 = 6.283185307179586476925287;
    if (t < 16)              { double s, c; sincos(-(PI2 * t) / 32.0, &s, &c); tws[TW_W32 + t] = make_float2((float)c, (float)s); }
    if (t >= 16 && t < 23)   { int j = t - 16; double s, c; sincos(-(PI2 * j) / 7.0,  &s, &c); tws[TW_W7 + j]  = make_float2((float)c, (float)s); }
    if (t >= 23 && t < 55)   { int j = t - 23; double s, c; sincos(-(PI2 * j) / 64.0, &s, &c); tws[TW_W64 + j] = make_float2((float)c, (float)s); }
    if (t >= 55 && t < 279)  { int j = t - 55;  int d7 = j >> 5, l = j & 31;
                               double s, c; sincos(-(PI2 * (d7 * l)) / 224.0, &s, &c);
                               tws[TW_T224 + j] = make_float2((float)c, (float)s); }
    if (t >= 279 && t < 727) { int j = t - 279; int d7 = j >> 6, l = j & 63;
                               double s, c; sincos(-(PI2 * (d7 * l)) / 448.0, &s, &c);
                               tws[TW_T448 + j] = make_float2((float)c, (float)s); }
    if (t >= 727 && t < 759) S[t - 727] = 0.0;
}

__global__ void k_build_p(const float* __restrict__ z, const float* __restrict__ zf,
                          const float* __restrict__ miu,
                          float2* __restrict__ p, float2* __restrict__ r, float2* __restrict__ b,
                          double* __restrict__ S) {
    float mu = fabsf(miu[0]);
    double acc = 0.0;
    for (int e = blockIdx.x * blockDim.x + threadIdx.x; e < DHWn; e += gridDim.x * blockDim.x) {
        int d = e / HWn, rem = e - d * HWn;
        int h = rem / Wn, w = rem - h * Wn;
        int hs = h + Hn / 2; if (hs >= Hn) hs -= Hn;
        int ws = w + Wn / 2; if (ws >= Wn) ws -= Wn;
        int src = d * HWn + hs * Wn + ws;
        float pr = fmaf(mu, z[src], zf[src]);
        float pi = fmaf(mu, z[DHWn + src], zf[DHWn + src]);
        float2 v = make_float2(pr, pi);
        p[e] = v; r[e] = v; b[e] = make_float2(0.f, 0.f);
        acc += (double)pr * pr + (double)pi * pi;
    }
    acc = waveReduce(acc);
    if ((threadIdx.x & 63) == 0) atomicAdd(&S[0], acc);
}

__global__ void k_build_coil(const float* __restrict__ cr, const float* __restrict__ ci,
                             float2* __restrict__ coil) {
    for (int e = blockIdx.x * blockDim.x + threadIdx.x; e < Cn * HWn; e += gridDim.x * blockDim.x) {
        int c = e / HWn, rem = e - c * HWn;
        int h = rem / Wn, w = rem - h * Wn;
        int hs = h + Hn / 2; if (hs >= Hn) hs -= Hn;
        int ws = w + Wn / 2; if (ws >= Wn) ws -= Wn;
        int src = c * HWn + hs * Wn + ws;
        coil[e] = make_float2(cr[src], ci[src]);
    }
}

// permuted + shifted + scaled mask: maskP[L*448 + h], line L holds true
// frequency column w(L) = 7*brev5(L&31) + (L>>5)
__global__ void k_build_mask(const int* __restrict__ mask, float* __restrict__ maskP) {
    for (int e = blockIdx.x * blockDim.x + threadIdx.x; e < HWn; e += gridDim.x * blockDim.x) {
        int L = e / Hn, h = e - L * Hn;
        int w = 7 * brev5(L & 31) + (L >> 5);
        int hs = h + Hn / 2; if (hs >= Hn) hs -= Hn;
        int ws = w + Wn / 2; if (ws >= Wn) ws -= Wn;
        maskP[e] = (float)mask[hs * Wn + ws] * (1.0f / (float)HWn);
    }
}

// ---------- forward row FFT (224 = 7*32 lane-FFT), coil-mul, write Y1T lines ----------
#define BPITCH 226
__global__ __launch_bounds__(256) void k_rowfft0(const float2* __restrict__ P,
                                                 const float2* __restrict__ coil,
                                                 float2* __restrict__ Y1T,
                                                 const float2* __restrict__ twg,
                                                 int chunkStart) {
    __shared__ float2 buf[8][BPITCH];
    int tid = threadIdx.x;
    int lane = tid & 63, wv = tid >> 6, hi = lane >> 5, l32 = lane & 31;
    int h0 = blockIdx.x * 8, d = blockIdx.y, cz = blockIdx.z;
    int row = h0 + 2 * wv + hi;
    const float2* w32g = twg + TW_W32;
    const float2* w7g  = twg + TW_W7;
    const float2* t224 = twg + TW_T224;

    const float2* prow = P + (size_t)d * HWn + (size_t)row * Wn;
    const float2* crow = coil + (size_t)(chunkStart + cz) * HWn + (size_t)row * Wn;

    float2 xb[7];
#pragma unroll
    for (int b = 0; b < 7; ++b) xb[b] = cmul(prow[32 * b + l32], crow[32 * b + l32]);

    // DFT7
    float2 y[7];
#pragma unroll
    for (int d7 = 0; d7 < 7; ++d7) {
        float2 s = xb[0];
#pragma unroll
        for (int b = 1; b < 7; ++b) s = cfma(xb[b], w7g[(b * d7) % 7], s);
        y[d7] = s;
    }
    // twiddle W224^{l32*d7} from table
#pragma unroll
    for (int d7 = 1; d7 < 7; ++d7) y[d7] = cmul(y[d7], t224[d7 * 32 + l32]);

    // FFT32 across each half-wave, DIF (select form — measured best)
#pragma unroll
    for (int s = 0; s < 5; ++s) {
        int dist = 16 >> s;
        float2 wst = w32g[(l32 & (dist - 1)) << s];
        bool h2 = (l32 & dist) != 0;
#pragma unroll
        for (int d7 = 0; d7 < 7; ++d7) {
            float2 t = shflx2(y[d7], dist);
            float2 sum = cadd(y[d7], t);
            float2 dif = cmul(csub(t, y[d7]), wst);
            y[d7] = h2 ? dif : sum;
        }
    }

    // deposit to LDS: line L = d7*32 + l32
#pragma unroll
    for (int d7 = 0; d7 < 7; ++d7) buf[2 * wv + hi][d7 * 32 + l32] = y[d7];
    __syncthreads();

    float2* img = Y1T + ((size_t)cz * Dn + d) * (size_t)HWn;
#pragma unroll
    for (int k = 0; k < 7; ++k) {
        int i = tid + k * 256;
        int hh = i & 7, L = i >> 3;
        img[(size_t)L * Hn + h0 + hh] = buf[hh][L];
    }
}

// ---------- column FFT448 + mask + IFFT448, pure register lane-FFT ----------
__global__ __launch_bounds__(256) void k_colfft(float2* __restrict__ Y1T,
                                                const float* __restrict__ maskP,
                                                const float2* __restrict__ twg) {
    __shared__ float2 tws[TW_NT];
    int tid = threadIdx.x;
    int lane = tid & 63, wv = tid >> 6;
    for (int i = tid; i < TW_NT; i += 256) tws[i] = twg[i];
    __syncthreads();

    const float2* w7t  = tws + TW_W7;
    const float2* w64t = tws + TW_W64;
    const float2* t448 = tws + TW_T448;

    int L = blockIdx.x * 4 + wv;
    int d = blockIdx.y, cz = blockIdx.z;
    float2* line = Y1T + ((size_t)cz * Dn + d) * (size_t)HWn + (size_t)L * Hn;

    float2 xb[7];
#pragma unroll
    for (int b = 0; b < 7; ++b) xb[b] = line[64 * b + lane];

    // forward DFT7
    float2 y[7];
#pragma unroll
    for (int d7 = 0; d7 < 7; ++d7) {
        float2 s = xb[0];
#pragma unroll
        for (int b = 1; b < 7; ++b) s = cfma(xb[b], w7t[(b * d7) % 7], s);
        y[d7] = s;
    }
    // twiddle W448^{lane*d7} from table (kept for inverse conj reuse)
    float2 tp[7];
#pragma unroll
    for (int d7 = 1; d7 < 7; ++d7) {
        tp[d7] = t448[d7 * 64 + lane];
        y[d7] = cmul(y[d7], tp[d7]);
    }

    // FFT64 across lanes, DIF (select form)
#pragma unroll
    for (int s = 0; s < 6; ++s) {
        int dist = 32 >> s;
        float2 wst = w64t[(lane & (dist - 1)) << s];
        bool hi = (lane & dist) != 0;
#pragma unroll
        for (int d7 = 0; d7 < 7; ++d7) {
            float2 t = shflx2(y[d7], dist);
            float2 sum = cadd(y[d7], t);
            float2 dif = cmul(csub(t, y[d7]), wst);
            y[d7] = hi ? dif : sum;
        }
    }

    // mask: lane holds H-freq index 7*brev6(lane)+d7
    int rb = (brev5(lane & 31) << 1) | (lane >> 5);
    const float* mrow = maskP + (size_t)L * Hn + 7 * rb;
#pragma unroll
    for (int d7 = 0; d7 < 7; ++d7) {
        float m = mrow[d7];
        y[d7].x *= m; y[d7].y *= m;
    }

    // inverse FFT64, DIT (select form)
#pragma unroll
    for (int s = 0; s < 6; ++s) {
        int dist = 1 << s;
        float2 wst = w64t[(lane & (dist - 1)) << (5 - s)];
        wst.y = -wst.y;
        bool hi = (lane & dist) != 0;
#pragma unroll
        for (int d7 = 0; d7 < 7; ++d7) {
            float2 t = shflx2(y[d7], dist);
            float2 uu = hi ? t : y[d7];
            float2 vv = hi ? y[d7] : t;
            float2 wtv = cmul(vv, wst);
            y[d7] = hi ? csub(uu, wtv) : cadd(uu, wtv);
        }
    }
#pragma unroll
    for (int d7 = 1; d7 < 7; ++d7) {
        float2 c = make_float2(tp[d7].x, -tp[d7].y);
        y[d7] = cmul(y[d7], c);
    }
#pragma unroll
    for (int b = 0; b < 7; ++b) {
        float2 s = y[0];
#pragma unroll
        for (int d7 = 1; d7 < 7; ++d7) {
            float2 wq = w7t[(b * d7) % 7]; wq.y = -wq.y;
            s = cfma(y[d7], wq, s);
        }
        xb[b] = s;
    }
#pragma unroll
    for (int b = 0; b < 7; ++b) line[64 * b + lane] = xb[b];
}

// ---------- fused inverse row FFT + conj-coil + coil-sum + q/dot epilogue ----------
// Double-buffered LDS strips: 1 barrier per coil. Coil row loads issued before
// next-strip prefetch so the accumulate's vmcnt wait doesn't drain the prefetch.
__global__ __launch_bounds__(256) void k_irow_combine(const float2* __restrict__ Y1T,
                                                      const float2* __restrict__ coil,
                                                      const float2* __restrict__ P,
                                                      float2* __restrict__ Q,
                                                      const float* __restrict__ miu,
                                                      double* __restrict__ S,
                                                      const float2* __restrict__ twg,
                                                      int cc, int chunkStart,
                                                      int first, int last, int it) {
    __shared__ float2 buf[2][8][BPITCH];
    int tid = threadIdx.x;
    int lane = tid & 63, wv = tid >> 6, hi = lane >> 5, l32 = lane & 31;
    int h0 = blockIdx.x * 8, d = blockIdx.y;
    int row = h0 + 2 * wv + hi;
    const float2* w32g = twg + TW_W32;
    const float2* w7g  = twg + TW_W7;
    const float2* t224 = twg + TW_T224;

    float2 tp[7];
#pragma unroll
    for (int d7 = 1; d7 < 7; ++d7) {
        float2 v = t224[d7 * 32 + l32];
        tp[d7] = make_float2(v.x, -v.y);   // conj (inverse twiddle)
    }

    float2 acc[7];
#pragma unroll
    for (int b = 0; b < 7; ++b) acc[b] = make_float2(0.f, 0.f);

    // stage strip 0 into buf[0]
    float2 pre[7];
    {
        const float2* img0 = Y1T + (size_t)d * HWn;
#pragma unroll
        for (int k = 0; k < 7; ++k) {
            int i = tid + k * 256;
            int hh = i & 7, L = i >> 3;
            pre[k] = img0[(size_t)L * Hn + h0 + hh];
        }
#pragma unroll
        for (int k = 0; k < 7; ++k) {
            int i = tid + k * 256;
            int hh = i & 7, L = i >> 3;
            buf[0][hh][L] = pre[k];
        }
    }
    __syncthreads();

    for (int cz = 0; cz < cc; ++cz) {
        int cur = cz & 1;
        // issue this coil's row loads FIRST (used at end of compute)
        const float2* crow = coil + (size_t)(chunkStart + cz) * HWn + (size_t)row * Wn;
        float2 cpre[7];
#pragma unroll
        for (int b = 0; b < 7; ++b) cpre[b] = crow[32 * b + l32];
        // then prefetch next strip (drains only at the ds_write below)
        if (cz + 1 < cc) {
            const float2* imgn = Y1T + ((size_t)(cz + 1) * Dn + d) * (size_t)HWn;
#pragma unroll
            for (int k = 0; k < 7; ++k) {
                int i = tid + k * 256;
                int hh = i & 7, L = i >> 3;
                pre[k] = imgn[(size_t)L * Hn + h0 + hh];
            }
        }

        // lane l32 reads line L = d7*32 + l32 (DIT-ready bit-rev order)
        float2 y[7];
#pragma unroll
        for (int d7 = 0; d7 < 7; ++d7) y[d7] = buf[cur][2 * wv + hi][d7 * 32 + l32];

        // inverse FFT32 across half-wave, DIT (select form)
#pragma unroll
        for (int s = 0; s < 5; ++s) {
            int dist = 1 << s;
            float2 wst = w32g[(l32 & (dist - 1)) << (4 - s)];
            wst.y = -wst.y;
            bool h2 = (l32 & dist) != 0;
#pragma unroll
            for (int d7 = 0; d7 < 7; ++d7) {
                float2 t = shflx2(y[d7], dist);
                float2 uu = h2 ? t : y[d7];
                float2 vv = h2 ? y[d7] : t;
                float2 wtv = cmul(vv, wst);
                y[d7] = h2 ? csub(uu, wtv) : cadd(uu, wtv);
            }
        }
        // conj twiddle W224^{-l32*d7}
#pragma unroll
        for (int d7 = 1; d7 < 7; ++d7) y[d7] = cmul(y[d7], tp[d7]);
        // inverse DFT7 + conj-coil accumulate
#pragma unroll
        for (int b = 0; b < 7; ++b) {
            float2 s = y[0];
#pragma unroll
            for (int d7 = 1; d7 < 7; ++d7) {
                float2 wq = w7g[(b * d7) % 7]; wq.y = -wq.y;
                s = cfma(y[d7], wq, s);
            }
            float2 c = cpre[b];
            acc[b].x += fmaf(s.x, c.x, s.y * c.y);
            acc[b].y += fmaf(s.y, c.x, -s.x * c.y);
        }

        // write next strip into the other buffer, one barrier per coil
        if (cz + 1 < cc) {
#pragma unroll
            for (int k = 0; k < 7; ++k) {
                int i = tid + k * 256;
                int hh = i & 7, L = i >> 3;
                buf[cur ^ 1][hh][L] = pre[k];
            }
        }
        __syncthreads();
    }

    // epilogue: q = mu*p + acc (or q += acc), dots on last chunk
    float mu = fabsf(miu[0]);
    const float2* prow = P + (size_t)d * HWn + (size_t)row * Wn;
    float2* qrow = Q + (size_t)d * HWn + (size_t)row * Wn;
    double ar = 0.0, ai = 0.0;
#pragma unroll
    for (int b = 0; b < 7; ++b) {
        float2 pv = prow[32 * b + l32];
        float2 s0;
        if (first) s0 = make_float2(fmaf(mu, pv.x, acc[b].x), fmaf(mu, pv.y, acc[b].y));
        else { float2 qv = qrow[32 * b + l32]; s0 = cadd(qv, acc[b]); }
        qrow[32 * b + l32] = s0;
        if (last) {
            ar += (double)(s0.x * pv.x + s0.y * pv.y);
            ai += (double)(s0.y * pv.x - s0.x * pv.y);
        }
    }
    if (last) {
        ar = waveReduce(ar);
        ai = waveReduce(ai);
        if ((threadIdx.x & 63) == 0) {
            atomicAdd(&S[8 + it], ar);
            atomicAdd(&S[16 + it], ai);
        }
    }
}

// ---------- CG scalar updates (float4 = 2 complex per lane) ----------
__global__ void k_update_br(const double* __restrict__ Sin, double* __restrict__ S, int it,
                            const float4* __restrict__ p, const float4* __restrict__ q,
                            float4* __restrict__ b, float4* __restrict__ r) {
    double rr = Sin[it], qr = Sin[8 + it], qi = Sin[16 + it];
    double den = qr * qr + qi * qi;
    float arf = (float)(rr * qr / den);
    float aif = (float)(-rr * qi / den);
    double acc = 0.0;
    const int N2 = DHWn / 2;
    for (int e = blockIdx.x * blockDim.x + threadIdx.x; e < N2; e += gridDim.x * blockDim.x) {
        float4 pv = p[e], qv = q[e], bv = b[e], rv = r[e];
        bv.x += arf * pv.x - aif * pv.y;  bv.y += arf * pv.y + aif * pv.x;
        bv.z += arf * pv.z - aif * pv.w;  bv.w += arf * pv.w + aif * pv.z;
        b[e] = bv;
        rv.x -= arf * qv.x - aif * qv.y;  rv.y -= arf * qv.y + aif * qv.x;
        rv.z -= arf * qv.z - aif * qv.w;  rv.w -= arf * qv.w + aif * qv.z;
        r[e] = rv;
        acc += (double)rv.x * rv.x + (double)rv.y * rv.y
             + (double)rv.z * rv.z + (double)rv.w * rv.w;
    }
    acc = waveReduce(acc);
    if ((threadIdx.x & 63) == 0) atomicAdd(&S[it + 1], acc);
}

__global__ void k_update_p(const double* __restrict__ S, int it,
                           const float4* __restrict__ r, float4* __restrict__ p) {
    float beta = (float)(S[it + 1] / S[it]);
    const int N2 = DHWn / 2;
    for (int e = blockIdx.x * blockDim.x + threadIdx.x; e < N2; e += gridDim.x * blockDim.x) {
        float4 rv = r[e], pv = p[e];
        p[e] = make_float4(fmaf(beta, pv.x, rv.x), fmaf(beta, pv.y, rv.y),
                           fmaf(beta, pv.z, rv.z), fmaf(beta, pv.w, rv.w));
    }
}

__global__ void k_output(const float2* __restrict__ b, float* __restrict__ out) {
    for (int e = blockIdx.x * blockDim.x + threadIdx.x; e < DHWn; e += gridDim.x * blockDim.x) {
        int d = e / HWn, rem = e - d * HWn;
        int h = rem / Wn, w = rem - h * Wn;
        int hs = h + Hn / 2; if (hs >= Hn) hs -= Hn;
        int ws = w + Wn / 2; if (ws >= Wn) ws -= Wn;
        float2 v = b[d * HWn + hs * Wn + ws];
        out[e] = v.x;
        out[DHWn + e] = v.y;
    }
}

extern "C" void kernel_launch(void* const* d_in, const int* in_sizes, int n_in,
                              void* d_out, int out_size, void* d_ws, size_t ws_size,
                              hipStream_t stream) {
    const float* z      = (const float*)d_in[0];
    const float* zf     = (const float*)d_in[1];
    const float* coil_r = (const float*)d_in[2];
    const float* coil_i = (const float*)d_in[3];
    const int*   maskp  = (const int*)d_in[4];
    const float* miu    = (const float*)d_in[5];
    float* out = (float*)d_out;

    char* w = (char*)d_ws;
    size_t off = 0;
    auto carve = [&](size_t bytes) -> void* {
        void* ptr = w + off;
        off += (bytes + 511) & ~(size_t)511;
        return ptr;
    };
    float2* P     = (float2*)carve((size_t)DHWn * 8);
    float2* R     = (float2*)carve((size_t)DHWn * 8);
    float2* Bv    = (float2*)carve((size_t)DHWn * 8);
    float2* Q     = (float2*)carve((size_t)DHWn * 8);
    float2* COIL  = (float2*)carve((size_t)Cn * HWn * 8);
    float*  MASKP = (float*)carve((size_t)HWn * 4);
    float2* TWS   = (float2*)carve(TW_NT * 8);
    double* S     = (double*)carve(64 * 8);

    size_t imgSet = (size_t)DHWn * 8;   // one coil-slot (12 slices), 9.63 MB
    int cc = 1;
    {
        const int opts[4] = {10, 5, 2, 1};
        for (int i = 0; i < 4; ++i) {
            if (off + (size_t)opts[i] * imgSet <= ws_size) { cc = opts[i]; break; }
        }
    }
    float2* Y1T = (float2*)carve((size_t)cc * imgSet);   // staged lines [c][d][L][h]
    int nch = Cn / cc;

    k_init_misc<<<1, 1024, 0, stream>>>(TWS, S);
    k_build_p<<<1024, 256, 0, stream>>>(z, zf, miu, P, R, Bv, S);
    k_build_coil<<<1024, 256, 0, stream>>>(coil_r, coil_i, COIL);
    k_build_mask<<<512, 256, 0, stream>>>(maskp, MASKP);

    for (int it = 0; it < 5; ++it) {
        for (int ch = 0; ch < nch; ++ch) {
            int cs = ch * cc;
            dim3 gf(Hn / 8, Dn, cc);   // 56 x 12 x cc
            dim3 gc(Wn / 4, Dn, cc);   // 56 x 12 x cc
            dim3 gi(Hn / 8, Dn);       // 56 x 12, loops over cc coils
            k_rowfft0<<<gf, 256, 0, stream>>>(P, COIL, Y1T, TWS, cs);
            k_colfft<<<gc, 256, 0, stream>>>(Y1T, MASKP, TWS);
            k_irow_combine<<<gi, 256, 0, stream>>>(Y1T, COIL, P, Q, miu, S, TWS,
                                                   cc, cs, ch == 0 ? 1 : 0,
                                                   ch == nch - 1 ? 1 : 0, it);
        }
        k_update_br<<<1024, 256, 0, stream>>>(S, S, it, (const float4*)P, (const float4*)Q,
                                              (float4*)Bv, (float4*)R);
        if (it < 4) k_update_p<<<1024, 256, 0, stream>>>(S, it, (const float4*)R, (float4*)P);
    }
    k_output<<<1024, 256, 0, stream>>>(Bv, out);
}

// Round 10
// 1248.825 us; speedup vs baseline: 1.1498x; 1.0168x over previous
//
#include <hip/hip_runtime.h>
#include <math.h>

// Problem constants (fixed shapes from setup_inputs)
#define Dn   12
#define Hn   448
#define Wn   224
#define HWn  (Hn*Wn)        // 100352
#define DHWn (Dn*HWn)       // 1204224
#define Cn   10

// Twiddle table (float2 in global):
#define TW_W32   0     // 16:  W32^j
#define TW_W7    16    // 7:   W7^j (kept in table but DFT7 uses literals)
#define TW_W64   23    // 32:  W64^j
#define TW_T224  55    // 224: W224^{d7*l32}  [d7*32+l32]
#define TW_T448  279   // 448: W448^{d7*lane} [d7*64+lane]
#define TW_NT    727

// W7^j = exp(-2*pi*i*j/7), compile-time (folds to literals under full unroll)
__device__ __constant__ const float W7R[7] = {
    1.0f,  0.62348980185873359f, -0.22252093395631445f, -0.90096886790241915f,
    -0.90096886790241915f, -0.22252093395631445f, 0.62348980185873359f };
__device__ __constant__ const float W7I[7] = {
    0.0f, -0.78183148246802980f, -0.97492791218182362f, -0.43388373911755823f,
    0.43388373911755823f,  0.97492791218182362f, 0.78183148246802980f };

// ---------- complex helpers ----------
__device__ __forceinline__ float2 cmul(float2 a, float2 b) {
    return make_float2(fmaf(a.x, b.x, -a.y * b.y), fmaf(a.x, b.y, a.y * b.x));
}
__device__ __forceinline__ float2 cfma(float2 a, float2 b, float2 acc) {
    acc.x = fmaf(a.x, b.x, fmaf(-a.y, b.y, acc.x));
    acc.y = fmaf(a.x, b.y, fmaf(a.y, b.x, acc.y));
    return acc;
}
// acc += a * (wr, sgn*wi) with literal wr/wi
__device__ __forceinline__ float2 cfma_lit(float2 a, float wr, float wi, float2 acc) {
    acc.x = fmaf(a.x, wr, fmaf(-a.y, wi, acc.x));
    acc.y = fmaf(a.x, wi, fmaf(a.y, wr, acc.y));
    return acc;
}
__device__ __forceinline__ float2 cadd(float2 a, float2 b) { return make_float2(a.x + b.x, a.y + b.y); }
__device__ __forceinline__ float2 csub(float2 a, float2 b) { return make_float2(a.x - b.x, a.y - b.y); }
__host__ __device__ constexpr int brev5(int i) {
    return ((i & 1) << 4) | ((i & 2) << 2) | (i & 4) | ((i & 8) >> 2) | ((i & 16) >> 4);
}

__device__ __forceinline__ float2 shflx2(float2 v, int m) {
    return make_float2(__shfl_xor(v.x, m, 64), __shfl_xor(v.y, m, 64));
}

__device__ __forceinline__ double waveReduce(double v) {
#pragma unroll
    for (int o = 32; o > 0; o >>= 1) v += __shfl_down(v, o, 64);
    return v;
}

// ---------- init kernels ----------
__global__ void k_init_misc(float2* __restrict__ tws, double* __restrict__ S) {
    int t = threadIdx.x;  // 1024 threads
    const double PI2 = 6.283185307179586476925287;
    if (t < 16)              { double s, c; sincos(-(PI2 * t) / 32.0, &s, &c); tws[TW_W32 + t] = make_float2((float)c, (float)s); }
    if (t >= 16 && t < 23)   { int j = t - 16; double s, c; sincos(-(PI2 * j) / 7.0,  &s, &c); tws[TW_W7 + j]  = make_float2((float)c, (float)s); }
    if (t >= 23 && t < 55)   { int j = t - 23; double s, c; sincos(-(PI2 * j) / 64.0, &s, &c); tws[TW_W64 + j] = make_float2((float)c, (float)s); }
    if (t >= 55 && t < 279)  { int j = t - 55;  int d7 = j >> 5, l = j & 31;
                               double s, c; sincos(-(PI2 * (d7 * l)) / 224.0, &s, &c);
                               tws[TW_T224 + j] = make_float2((float)c, (float)s); }
    if (t >= 279 && t < 727) { int j = t - 279; int d7 = j >> 6, l = j & 63;
                               double s, c; sincos(-(PI2 * (d7 * l)) / 448.0, &s, &c);
                               tws[TW_T448 + j] = make_float2((float)c, (float)s); }
    if (t >= 727 && t < 759) S[t - 727] = 0.0;
}

__global__ void k_build_p(const float* __restrict__ z, const float* __restrict__ zf,
                          const float* __restrict__ miu,
                          float2* __restrict__ p, float2* __restrict__ r, float2* __restrict__ b,
                          double* __restrict__ S) {
    float mu = fabsf(miu[0]);
    double acc = 0.0;
    for (int e = blockIdx.x * blockDim.x + threadIdx.x; e < DHWn; e += gridDim.x * blockDim.x) {
        int d = e / HWn, rem = e - d * HWn;
        int h = rem / Wn, w = rem - h * Wn;
        int hs = h + Hn / 2; if (hs >= Hn) hs -= Hn;
        int ws = w + Wn / 2; if (ws >= Wn) ws -= Wn;
        int src = d * HWn + hs * Wn + ws;
        float pr = fmaf(mu, z[src], zf[src]);
        float pi = fmaf(mu, z[DHWn + src], zf[DHWn + src]);
        float2 v = make_float2(pr, pi);
        p[e] = v; r[e] = v; b[e] = make_float2(0.f, 0.f);
        acc += (double)pr * pr + (double)pi * pi;
    }
    acc = waveReduce(acc);
    if ((threadIdx.x & 63) == 0) atomicAdd(&S[0], acc);
}

__global__ void k_build_coil(const float* __restrict__ cr, const float* __restrict__ ci,
                             float2* __restrict__ coil) {
    for (int e = blockIdx.x * blockDim.x + threadIdx.x; e < Cn * HWn; e += gridDim.x * blockDim.x) {
        int c = e / HWn, rem = e - c * HWn;
        int h = rem / Wn, w = rem - h * Wn;
        int hs = h + Hn / 2; if (hs >= Hn) hs -= Hn;
        int ws = w + Wn / 2; if (ws >= Wn) ws -= Wn;
        int src = c * HWn + hs * Wn + ws;
        coil[e] = make_float2(cr[src], ci[src]);
    }
}

// permuted + shifted + scaled mask: maskP[L*448 + h], line L holds true
// frequency column w(L) = 7*brev5(L&31) + (L>>5)
__global__ void k_build_mask(const int* __restrict__ mask, float* __restrict__ maskP) {
    for (int e = blockIdx.x * blockDim.x + threadIdx.x; e < HWn; e += gridDim.x * blockDim.x) {
        int L = e / Hn, h = e - L * Hn;
        int w = 7 * brev5(L & 31) + (L >> 5);
        int hs = h + Hn / 2; if (hs >= Hn) hs -= Hn;
        int ws = w + Wn / 2; if (ws >= Wn) ws -= Wn;
        maskP[e] = (float)mask[hs * Wn + ws] * (1.0f / (float)HWn);
    }
}

// ---------- forward row FFT (224 = 7*32 lane-FFT), coil-mul, write Y1T lines ----------
#define BPITCH 226
__global__ __launch_bounds__(256) void k_rowfft0(const float2* __restrict__ P,
                                                 const float2* __restrict__ coil,
                                                 float2* __restrict__ Y1T,
                                                 const float2* __restrict__ twg,
                                                 int chunkStart) {
    __shared__ float2 buf[8][BPITCH];
    int tid = threadIdx.x;
    int lane = tid & 63, wv = tid >> 6, hi = lane >> 5, l32 = lane & 31;
    int h0 = blockIdx.x * 8, d = blockIdx.y, cz = blockIdx.z;
    int row = h0 + 2 * wv + hi;
    const float2* w32g = twg + TW_W32;
    const float2* t224 = twg + TW_T224;

    const float2* prow = P + (size_t)d * HWn + (size_t)row * Wn;
    const float2* crow = coil + (size_t)(chunkStart + cz) * HWn + (size_t)row * Wn;

    float2 xb[7];
#pragma unroll
    for (int b = 0; b < 7; ++b) xb[b] = cmul(prow[32 * b + l32], crow[32 * b + l32]);

    // DFT7 (literal twiddles)
    float2 y[7];
#pragma unroll
    for (int d7 = 0; d7 < 7; ++d7) {
        float2 s = xb[0];
#pragma unroll
        for (int b = 1; b < 7; ++b) s = cfma_lit(xb[b], W7R[(b * d7) % 7], W7I[(b * d7) % 7], s);
        y[d7] = s;
    }
    // twiddle W224^{l32*d7} from table
#pragma unroll
    for (int d7 = 1; d7 < 7; ++d7) y[d7] = cmul(y[d7], t224[d7 * 32 + l32]);

    // FFT32 across each half-wave, DIF (select form — measured best)
#pragma unroll
    for (int s = 0; s < 5; ++s) {
        int dist = 16 >> s;
        float2 wst = w32g[(l32 & (dist - 1)) << s];
        bool h2 = (l32 & dist) != 0;
#pragma unroll
        for (int d7 = 0; d7 < 7; ++d7) {
            float2 t = shflx2(y[d7], dist);
            float2 sum = cadd(y[d7], t);
            float2 dif = cmul(csub(t, y[d7]), wst);
            y[d7] = h2 ? dif : sum;
        }
    }

    // deposit to LDS: line L = d7*32 + l32
#pragma unroll
    for (int d7 = 0; d7 < 7; ++d7) buf[2 * wv + hi][d7 * 32 + l32] = y[d7];
    __syncthreads();

    float2* img = Y1T + ((size_t)cz * Dn + d) * (size_t)HWn;
#pragma unroll
    for (int k = 0; k < 7; ++k) {
        int i = tid + k * 256;
        int hh = i & 7, L = i >> 3;
        img[(size_t)L * Hn + h0 + hh] = buf[hh][L];
    }
}

// ---------- column FFT448 + mask + IFFT448, pure register lane-FFT, no LDS ----------
__global__ __launch_bounds__(256) void k_colfft(float2* __restrict__ Y1T,
                                                const float* __restrict__ maskP,
                                                const float2* __restrict__ twg) {
    int tid = threadIdx.x;
    int lane = tid & 63, wv = tid >> 6;
    const float2* w64t = twg + TW_W64;   // 32 entries, L1-resident
    const float2* t448 = twg + TW_T448;  // per-lane coalesced

    int L = blockIdx.x * 4 + wv;
    int d = blockIdx.y, cz = blockIdx.z;
    float2* line = Y1T + ((size_t)cz * Dn + d) * (size_t)HWn + (size_t)L * Hn;

    float2 xb[7];
#pragma unroll
    for (int b = 0; b < 7; ++b) xb[b] = line[64 * b + lane];

    // twiddles W448^{lane*d7} (reused conjugated in the inverse pass)
    float2 tp[7];
#pragma unroll
    for (int d7 = 1; d7 < 7; ++d7) tp[d7] = t448[d7 * 64 + lane];

    // forward DFT7 (literal twiddles)
    float2 y[7];
#pragma unroll
    for (int d7 = 0; d7 < 7; ++d7) {
        float2 s = xb[0];
#pragma unroll
        for (int b = 1; b < 7; ++b) s = cfma_lit(xb[b], W7R[(b * d7) % 7], W7I[(b * d7) % 7], s);
        y[d7] = s;
    }
#pragma unroll
    for (int d7 = 1; d7 < 7; ++d7) y[d7] = cmul(y[d7], tp[d7]);

    // FFT64 across lanes, DIF (select form)
#pragma unroll
    for (int s = 0; s < 6; ++s) {
        int dist = 32 >> s;
        float2 wst = w64t[(lane & (dist - 1)) << s];
        bool hi = (lane & dist) != 0;
#pragma unroll
        for (int d7 = 0; d7 < 7; ++d7) {
            float2 t = shflx2(y[d7], dist);
            float2 sum = cadd(y[d7], t);
            float2 dif = cmul(csub(t, y[d7]), wst);
            y[d7] = hi ? dif : sum;
        }
    }

    // mask: lane holds H-freq index 7*brev6(lane)+d7
    int rb = (brev5(lane & 31) << 1) | (lane >> 5);
    const float* mrow = maskP + (size_t)L * Hn + 7 * rb;
#pragma unroll
    for (int d7 = 0; d7 < 7; ++d7) {
        float m = mrow[d7];
        y[d7].x *= m; y[d7].y *= m;
    }

    // inverse FFT64, DIT (select form)
#pragma unroll
    for (int s = 0; s < 6; ++s) {
        int dist = 1 << s;
        float2 wst = w64t[(lane & (dist - 1)) << (5 - s)];
        wst.y = -wst.y;
        bool hi = (lane & dist) != 0;
#pragma unroll
        for (int d7 = 0; d7 < 7; ++d7) {
            float2 t = shflx2(y[d7], dist);
            float2 uu = hi ? t : y[d7];
            float2 vv = hi ? y[d7] : t;
            float2 wtv = cmul(vv, wst);
            y[d7] = hi ? csub(uu, wtv) : cadd(uu, wtv);
        }
    }
#pragma unroll
    for (int d7 = 1; d7 < 7; ++d7) {
        float2 c = make_float2(tp[d7].x, -tp[d7].y);
        y[d7] = cmul(y[d7], c);
    }
    // inverse DFT7 (literal conj twiddles)
#pragma unroll
    for (int b = 0; b < 7; ++b) {
        float2 s = y[0];
#pragma unroll
        for (int d7 = 1; d7 < 7; ++d7)
            s = cfma_lit(y[d7], W7R[(b * d7) % 7], -W7I[(b * d7) % 7], s);
        xb[b] = s;
    }
#pragma unroll
    for (int b = 0; b < 7; ++b) line[64 * b + lane] = xb[b];
}

// ---------- fused inverse row FFT + conj-coil + coil-sum + q/dot epilogue ----------
// Double-buffered LDS strips: 1 barrier per coil. Coil row loads issued before
// next-strip prefetch so the accumulate's vmcnt wait doesn't drain the prefetch.
__global__ __launch_bounds__(256) void k_irow_combine(const float2* __restrict__ Y1T,
                                                      const float2* __restrict__ coil,
                                                      const float2* __restrict__ P,
                                                      float2* __restrict__ Q,
                                                      const float* __restrict__ miu,
                                                      double* __restrict__ S,
                                                      const float2* __restrict__ twg,
                                                      int cc, int chunkStart,
                                                      int first, int last, int it) {
    __shared__ float2 buf[2][8][BPITCH];
    int tid = threadIdx.x;
    int lane = tid & 63, wv = tid >> 6, hi = lane >> 5, l32 = lane & 31;
    int h0 = blockIdx.x * 8, d = blockIdx.y;
    int row = h0 + 2 * wv + hi;
    const float2* w32g = twg + TW_W32;
    const float2* t224 = twg + TW_T224;

    float2 tp[7];
#pragma unroll
    for (int d7 = 1; d7 < 7; ++d7) {
        float2 v = t224[d7 * 32 + l32];
        tp[d7] = make_float2(v.x, -v.y);   // conj (inverse twiddle)
    }

    float2 acc[7];
#pragma unroll
    for (int b = 0; b < 7; ++b) acc[b] = make_float2(0.f, 0.f);

    // stage strip 0 into buf[0]
    float2 pre[7];
    {
        const float2* img0 = Y1T + (size_t)d * HWn;
#pragma unroll
        for (int k = 0; k < 7; ++k) {
            int i = tid + k * 256;
            int hh = i & 7, L = i >> 3;
            pre[k] = img0[(size_t)L * Hn + h0 + hh];
        }
#pragma unroll
        for (int k = 0; k < 7; ++k) {
            int i = tid + k * 256;
            int hh = i & 7, L = i >> 3;
            buf[0][hh][L] = pre[k];
        }
    }
    __syncthreads();

    for (int cz = 0; cz < cc; ++cz) {
        int cur = cz & 1;
        // issue this coil's row loads FIRST (used at end of compute)
        const float2* crow = coil + (size_t)(chunkStart + cz) * HWn + (size_t)row * Wn;
        float2 cpre[7];
#pragma unroll
        for (int b = 0; b < 7; ++b) cpre[b] = crow[32 * b + l32];
        // then prefetch next strip (drains only at the ds_write below)
        if (cz + 1 < cc) {
            const float2* imgn = Y1T + ((size_t)(cz + 1) * Dn + d) * (size_t)HWn;
#pragma unroll
            for (int k = 0; k < 7; ++k) {
                int i = tid + k * 256;
                int hh = i & 7, L = i >> 3;
                pre[k] = imgn[(size_t)L * Hn + h0 + hh];
            }
        }

        // lane l32 reads line L = d7*32 + l32 (DIT-ready bit-rev order)
        float2 y[7];
#pragma unroll
        for (int d7 = 0; d7 < 7; ++d7) y[d7] = buf[cur][2 * wv + hi][d7 * 32 + l32];

        // inverse FFT32 across half-wave, DIT (select form)
#pragma unroll
        for (int s = 0; s < 5; ++s) {
            int dist = 1 << s;
            float2 wst = w32g[(l32 & (dist - 1)) << (4 - s)];
            wst.y = -wst.y;
            bool h2 = (l32 & dist) != 0;
#pragma unroll
            for (int d7 = 0; d7 < 7; ++d7) {
                float2 t = shflx2(y[d7], dist);
                float2 uu = h2 ? t : y[d7];
                float2 vv = h2 ? y[d7] : t;
                float2 wtv = cmul(vv, wst);
                y[d7] = h2 ? csub(uu, wtv) : cadd(uu, wtv);
            }
        }
        // conj twiddle W224^{-l32*d7}
#pragma unroll
        for (int d7 = 1; d7 < 7; ++d7) y[d7] = cmul(y[d7], tp[d7]);
        // inverse DFT7 (literal conj twiddles) + conj-coil accumulate
#pragma unroll
        for (int b = 0; b < 7; ++b) {
            float2 s = y[0];
#pragma unroll
            for (int d7 = 1; d7 < 7; ++d7)
                s = cfma_lit(y[d7], W7R[(b * d7) % 7], -W7I[(b * d7) % 7], s);
            float2 c = cpre[b];
            acc[b].x += fmaf(s.x, c.x, s.y * c.y);
            acc[b].y += fmaf(s.y, c.x, -s.x * c.y);
        }

        // write next strip into the other buffer, one barrier per coil
        if (cz + 1 < cc) {
#pragma unroll
            for (int k = 0; k < 7; ++k) {
                int i = tid + k * 256;
                int hh = i & 7, L = i >> 3;
                buf[cur ^ 1][hh][L] = pre[k];
            }
        }
        __syncthreads();
    }

    // epilogue: q = mu*p + acc (or q += acc), dots on last chunk
    float mu = fabsf(miu[0]);
    const float2* prow = P + (size_t)d * HWn + (size_t)row * Wn;
    float2* qrow = Q + (size_t)d * HWn + (size_t)row * Wn;
    double ar = 0.0, ai = 0.0;
#pragma unroll
    for (int b = 0; b < 7; ++b) {
        float2 pv = prow[32 * b + l32];
        float2 s0;
        if (first) s0 = make_float2(fmaf(mu, pv.x, acc[b].x), fmaf(mu, pv.y, acc[b].y));
        else { float2 qv = qrow[32 * b + l32]; s0 = cadd(qv, acc[b]); }
        qrow[32 * b + l32] = s0;
        if (last) {
            ar += (double)(s0.x * pv.x + s0.y * pv.y);
            ai += (double)(s0.y * pv.x - s0.x * pv.y);
        }
    }
    if (last) {
        ar = waveReduce(ar);
        ai = waveReduce(ai);
        if ((threadIdx.x & 63) == 0) {
            atomicAdd(&S[8 + it], ar);
            atomicAdd(&S[16 + it], ai);
        }
    }
}

// ---------- CG scalar updates (float4 = 2 complex per lane) ----------
__global__ void k_update_br(const double* __restrict__ Sin, double* __restrict__ S, int it,
                            const float4* __restrict__ p, const float4* __restrict__ q,
                            float4* __restrict__ b, float4* __restrict__ r) {
    double rr = Sin[it], qr = Sin[8 + it], qi = Sin[16 + it];
    double den = qr * qr + qi * qi;
    float arf = (float)(rr * qr / den);
    float aif = (float)(-rr * qi / den);
    double acc = 0.0;
    const int N2 = DHWn / 2;
    for (int e = blockIdx.x * blockDim.x + threadIdx.x; e < N2; e += gridDim.x * blockDim.x) {
        float4 pv = p[e], qv = q[e], bv = b[e], rv = r[e];
        bv.x += arf * pv.x - aif * pv.y;  bv.y += arf * pv.y + aif * pv.x;
        bv.z += arf * pv.z - aif * pv.w;  bv.w += arf * pv.w + aif * pv.z;
        b[e] = bv;
        rv.x -= arf * qv.x - aif * qv.y;  rv.y -= arf * qv.y + aif * qv.x;
        rv.z -= arf * qv.z - aif * qv.w;  rv.w -= arf * qv.w + aif * qv.z;
        r[e] = rv;
        acc += (double)rv.x * rv.x + (double)rv.y * rv.y
             + (double)rv.z * rv.z + (double)rv.w * rv.w;
    }
    acc = waveReduce(acc);
    if ((threadIdx.x & 63) == 0) atomicAdd(&S[it + 1], acc);
}

__global__ void k_update_p(const double* __restrict__ S, int it,
                           const float4* __restrict__ r, float4* __restrict__ p) {
    float beta = (float)(S[it + 1] / S[it]);
    const int N2 = DHWn / 2;
    for (int e = blockIdx.x * blockDim.x + threadIdx.x; e < N2; e += gridDim.x * blockDim.x) {
        float4 rv = r[e], pv = p[e];
        p[e] = make_float4(fmaf(beta, pv.x, rv.x), fmaf(beta, pv.y, rv.y),
                           fmaf(beta, pv.z, rv.z), fmaf(beta, pv.w, rv.w));
    }
}

__global__ void k_output(const float2* __restrict__ b, float* __restrict__ out) {
    for (int e = blockIdx.x * blockDim.x + threadIdx.x; e < DHWn; e += gridDim.x * blockDim.x) {
        int d = e / HWn, rem = e - d * HWn;
        int h = rem / Wn, w = rem - h * Wn;
        int hs = h + Hn / 2; if (hs >= Hn) hs -= Hn;
        int ws = w + Wn / 2; if (ws >= Wn) ws -= Wn;
        float2 v = b[d * HWn + hs * Wn + ws];
        out[e] = v.x;
        out[DHWn + e] = v.y;
    }
}

extern "C" void kernel_launch(void* const* d_in, const int* in_sizes, int n_in,
                              void* d_out, int out_size, void* d_ws, size_t ws_size,
                              hipStream_t stream) {
    const float* z      = (const float*)d_in[0];
    const float* zf     = (const float*)d_in[1];
    const float* coil_r = (const float*)d_in[2];
    const float* coil_i = (const float*)d_in[3];
    const int*   maskp  = (const int*)d_in[4];
    const float* miu    = (const float*)d_in[5];
    float* out = (float*)d_out;

    char* w = (char*)d_ws;
    size_t off = 0;
    auto carve = [&](size_t bytes) -> void* {
        void* ptr = w + off;
        off += (bytes + 511) & ~(size_t)511;
        return ptr;
    };
    float2* P     = (float2*)carve((size_t)DHWn * 8);
    float2* R     = (float2*)carve((size_t)DHWn * 8);
    float2* Bv    = (float2*)carve((size_t)DHWn * 8);
    float2* Q     = (float2*)carve((size_t)DHWn * 8);
    float2* COIL  = (float2*)carve((size_t)Cn * HWn * 8);
    float*  MASKP = (float*)carve((size_t)HWn * 4);
    float2* TWS   = (float2*)carve(TW_NT * 8);
    double* S     = (double*)carve(64 * 8);

    size_t imgSet = (size_t)DHWn * 8;   // one coil-slot (12 slices), 9.63 MB
    int cc = 1;
    {
        const int opts[4] = {10, 5, 2, 1};
        for (int i = 0; i < 4; ++i) {
            if (off + (size_t)opts[i] * imgSet <= ws_size) { cc = opts[i]; break; }
        }
    }
    float2* Y1T = (float2*)carve((size_t)cc * imgSet);   // staged lines [c][d][L][h]
    int nch = Cn / cc;

    k_init_misc<<<1, 1024, 0, stream>>>(TWS, S);
    k_build_p<<<1024, 256, 0, stream>>>(z, zf, miu, P, R, Bv, S);
    k_build_coil<<<1024, 256, 0, stream>>>(coil_r, coil_i, COIL);
    k_build_mask<<<512, 256, 0, stream>>>(maskp, MASKP);

    for (int it = 0; it < 5; ++it) {
        for (int ch = 0; ch < nch; ++ch) {
            int cs = ch * cc;
            dim3 gf(Hn / 8, Dn, cc);   // 56 x 12 x cc
            dim3 gc(Wn / 4, Dn, cc);   // 56 x 12 x cc
            dim3 gi(Hn / 8, Dn);       // 56 x 12, loops over cc coils
            k_rowfft0<<<gf, 256, 0, stream>>>(P, COIL, Y1T, TWS, cs);
            k_colfft<<<gc, 256, 0, stream>>>(Y1T, MASKP, TWS);
            k_irow_combine<<<gi, 256, 0, stream>>>(Y1T, COIL, P, Q, miu, S, TWS,
                                                   cc, cs, ch == 0 ? 1 : 0,
                                                   ch == nch - 1 ? 1 : 0, it);
        }
        k_update_br<<<1024, 256, 0, stream>>>(S, S, it, (const float4*)P, (const float4*)Q,
                                              (float4*)Bv, (float4*)R);
        if (it < 4) k_update_p<<<1024, 256, 0, stream>>>(S, it, (const float4*)R, (float4*)P);
    }
    k_output<<<1024, 256, 0, stream>>>(Bv, out);
}